// Round 10
// baseline (1442.607 us; speedup 1.0000x reference)
//
#include <hip/hip_runtime.h>

#define S_LEN 4096
#define BATCH 4
#define NROWS 16384   // S*B
#define DIM   1024
#define CHUNK 32
#define NCHUNK (S_LEN / CHUNK)

typedef __attribute__((ext_vector_type(8))) short short8;
typedef __attribute__((ext_vector_type(4))) float floatx4;
typedef _Float16 half_t;
typedef __attribute__((ext_vector_type(8))) _Float16 half8;

__device__ __forceinline__ float bf2f(short s) {
    union { unsigned int u; float f; } c;
    c.u = ((unsigned int)(unsigned short)s) << 16;
    return c.f;
}
__device__ __forceinline__ short f2bf(float f) {
    union { float f; unsigned int u; } c; c.f = f;
    unsigned int r = c.u + 0x7fffu + ((c.u >> 16) & 1u);
    return (short)(r >> 16);
}
// split fp32 -> bf16 hi + bf16 lo (a ~= hi + lo, rel err ~2^-16)
__device__ __forceinline__ void split_bf16(float x, short& hi, short& lo) {
    short h = f2bf(x);
    hi = h;
    lo = f2bf(x - bf2f(h));
}

// 16-lane (DPP row) all-reduce sum: quad_perm xor1, xor2, row_ror:4, row_ror:8.
__device__ __forceinline__ float row16_allreduce(float x) {
    union fi { float f; int i; };
    fi a, b;
    a.f = x;
    b.i = __builtin_amdgcn_update_dpp(0, a.i, 0xB1,  0xF, 0xF, true); a.f += b.f; // xor1
    b.i = __builtin_amdgcn_update_dpp(0, a.i, 0x4E,  0xF, 0xF, true); a.f += b.f; // xor2
    b.i = __builtin_amdgcn_update_dpp(0, a.i, 0x124, 0xF, 0xF, true); a.f += b.f; // ror4
    b.i = __builtin_amdgcn_update_dpp(0, a.i, 0x128, 0xF, 0xF, true); a.f += b.f; // ror8
    return a.f;
}

// W[K][N] fp32 row-major -> Wt[N][K]  (small fp32 transpose, used for Wb)
__global__ __launch_bounds__(256) void transpose_k(const float* __restrict__ W,
                                                   float* __restrict__ Wt,
                                                   int K, int N) {
    int idx = blockIdx.x * 256 + threadIdx.x;
    if (idx >= N * K) return;
    int n = idx / K;
    int k = idx - n * K;
    Wt[idx] = W[k * N + n];
}

// W[K][N] fp32 -> transposed split-bf16 planes Wth/Wtl [N][K]
__global__ __launch_bounds__(256) void transpose_split(const float* __restrict__ W,
                                                       short* __restrict__ Wth,
                                                       short* __restrict__ Wtl,
                                                       int K, int N) {
    int idx = blockIdx.x * 256 + threadIdx.x;
    if (idx >= N * K) return;
    int n = idx / K;
    int k = idx - n * K;
    short h, l;
    split_bf16(W[k * N + n], h, l);
    Wth[idx] = h;
    Wtl[idx] = l;
}

// fp32 stream -> split-bf16 planes (8 elems/thread, coalesced)
__global__ __launch_bounds__(256) void split_f32(const float* __restrict__ X,
                                                 short* __restrict__ Xh,
                                                 short* __restrict__ Xl) {
    size_t idx = ((size_t)blockIdx.x * 256 + threadIdx.x) * 8;
    floatx4 a = *(const floatx4*)(X + idx);
    floatx4 b = *(const floatx4*)(X + idx + 4);
    short8 h, l;
    #pragma unroll
    for (int j = 0; j < 4; ++j) {
        short hh, ll;
        split_bf16(a[j], hh, ll); h[j] = hh; l[j] = ll;
        split_bf16(b[j], hh, ll); h[4 + j] = hh; l[4 + j] = ll;
    }
    *(short8*)(Xh + idx) = h;
    *(short8*)(Xl + idx) = l;
}

// fp16 stream -> split-bf16 planes (exact: fp16 = bf16hi + bf16lo)
__global__ __launch_bounds__(256) void split_f16(const half_t* __restrict__ X,
                                                 short* __restrict__ Xh,
                                                 short* __restrict__ Xl) {
    size_t idx = ((size_t)blockIdx.x * 256 + threadIdx.x) * 8;
    half8 a = *(const half8*)(X + idx);
    short8 h, l;
    #pragma unroll
    for (int j = 0; j < 8; ++j) {
        short hh, ll;
        split_bf16((float)a[j], hh, ll); h[j] = hh; l[j] = ll;
    }
    *(short8*)(Xh + idx) = h;
    *(short8*)(Xl + idx) = l;
}

// C = A[M,K] @ Bt[N,K]^T with pre-split bf16 hi/lo planes for A and B.
// 128x128 tile, 4 waves (2x2), 4x4 16x16 frags/wave, 3-term MFMA, fp32 acc.
// MODE 0: fp32 out at row*N+col (+ optional fp32 bias)
// MODE 1: fp16 out at row*2048 + (col>>6)*128 + (col&63)   (dpfp staging layout)
template <int MODE>
__global__ __launch_bounds__(256) void gemm_sb(const short* __restrict__ Ah,
                                               const short* __restrict__ Al,
                                               const short* __restrict__ Bh,
                                               const short* __restrict__ Bl,
                                               void* __restrict__ Cout,
                                               const float* __restrict__ bias,
                                               int N, int K) {
    __shared__ __align__(16) short As_h[128][40], As_l[128][40];   // 20 KB
    __shared__ __align__(16) short Bs_h[128][40], Bs_l[128][40];   // 20 KB
    const int tid  = threadIdx.x;
    const int wave = tid >> 6, lane = tid & 63;
    const int wr = wave >> 1, wc = wave & 1;       // 2x2 wave grid
    const int row0 = blockIdx.x * 128, col0 = blockIdx.y * 128;
    const int lr = tid >> 1, lc = (tid & 1) * 16;  // staging: 128 rows x 2 groups of 16
    const short* Aph = Ah + (size_t)(row0 + lr) * K + lc;
    const short* Apl = Al + (size_t)(row0 + lr) * K + lc;
    const short* Bph = Bh + (size_t)(col0 + lr) * K + lc;
    const short* Bpl = Bl + (size_t)(col0 + lr) * K + lc;
    const int fr = lane & 15;                      // frag row within 16
    const int ak = (lane >> 4) * 8;                // k-slice start
    floatx4 acc[4][4];
    #pragma unroll
    for (int m = 0; m < 4; ++m)
        #pragma unroll
        for (int n = 0; n < 4; ++n) acc[m][n] = (floatx4){0.f, 0.f, 0.f, 0.f};

    for (int k0 = 0; k0 < K; k0 += 32) {
        short8 vah0 = *(const short8*)(Aph + k0);
        short8 vah1 = *(const short8*)(Aph + k0 + 8);
        short8 val0 = *(const short8*)(Apl + k0);
        short8 val1 = *(const short8*)(Apl + k0 + 8);
        short8 vbh0 = *(const short8*)(Bph + k0);
        short8 vbh1 = *(const short8*)(Bph + k0 + 8);
        short8 vbl0 = *(const short8*)(Bpl + k0);
        short8 vbl1 = *(const short8*)(Bpl + k0 + 8);
        *(short8*)&As_h[lr][lc]     = vah0;
        *(short8*)&As_h[lr][lc + 8] = vah1;
        *(short8*)&As_l[lr][lc]     = val0;
        *(short8*)&As_l[lr][lc + 8] = val1;
        *(short8*)&Bs_h[lr][lc]     = vbh0;
        *(short8*)&Bs_h[lr][lc + 8] = vbh1;
        *(short8*)&Bs_l[lr][lc]     = vbl0;
        *(short8*)&Bs_l[lr][lc + 8] = vbl1;
        __syncthreads();

        short8 afh[4], afl[4], bfh[4], bfl[4];
        #pragma unroll
        for (int m = 0; m < 4; ++m) {
            afh[m] = *(const short8*)&As_h[wr * 64 + m * 16 + fr][ak];
            afl[m] = *(const short8*)&As_l[wr * 64 + m * 16 + fr][ak];
        }
        #pragma unroll
        for (int n = 0; n < 4; ++n) {
            bfh[n] = *(const short8*)&Bs_h[wc * 64 + n * 16 + fr][ak];
            bfl[n] = *(const short8*)&Bs_l[wc * 64 + n * 16 + fr][ak];
        }
        #pragma unroll
        for (int m = 0; m < 4; ++m)
            #pragma unroll
            for (int n = 0; n < 4; ++n) {
                acc[m][n] = __builtin_amdgcn_mfma_f32_16x16x32_bf16(afh[m], bfh[n], acc[m][n], 0, 0, 0);
                acc[m][n] = __builtin_amdgcn_mfma_f32_16x16x32_bf16(afh[m], bfl[n], acc[m][n], 0, 0, 0);
                acc[m][n] = __builtin_amdgcn_mfma_f32_16x16x32_bf16(afl[m], bfh[n], acc[m][n], 0, 0, 0);
            }
        __syncthreads();
    }
    // C/D layout (verified m89/m91): col = lane&15, row = (lane>>4)*4 + reg
    #pragma unroll
    for (int m = 0; m < 4; ++m) {
        const int crow = row0 + wr * 64 + m * 16 + (lane >> 4) * 4;
        #pragma unroll
        for (int n = 0; n < 4; ++n) {
            const int col = col0 + wc * 64 + n * 16 + (lane & 15);
            #pragma unroll
            for (int r = 0; r < 4; ++r) {
                int row = crow + r;
                float v = acc[m][n][r];
                if (MODE == 0) {
                    float bb = bias ? bias[col] : 0.f;
                    ((float*)Cout)[(size_t)row * N + col] = v + bb;
                } else {
                    ((half_t*)Cout)[(size_t)row * 2048 + (col >> 6) * 128 + (col & 63)] = (half_t)v;
                }
            }
        }
    }
}

// beta = sigmoid(x @ Wb); one wave per row, Wbt fp32 [16][1024]
__global__ __launch_bounds__(256) void beta_kernel(const float* __restrict__ X,
                                                   const float* __restrict__ Wbt,
                                                   float* __restrict__ Beta) {
    int wid  = (blockIdx.x * 256 + threadIdx.x) >> 6;
    int lane = threadIdx.x & 63;
    if (wid >= NROWS) return;
    const float* xr = X + (size_t)wid * DIM + lane * 16;
    float xv[16];
    #pragma unroll
    for (int j = 0; j < 4; ++j) {
        floatx4 v = *(const floatx4*)(xr + j * 4);
        #pragma unroll
        for (int e = 0; e < 4; ++e) xv[j * 4 + e] = v[e];
    }
    #pragma unroll 1
    for (int h = 0; h < 16; ++h) {
        const float* wr = Wbt + h * DIM + lane * 16;
        float s = 0.f;
        #pragma unroll
        for (int j = 0; j < 4; ++j) {
            floatx4 v = *(const floatx4*)(wr + j * 4);
            #pragma unroll
            for (int e = 0; e < 4; ++e) s = fmaf(xv[j * 4 + e], v[e], s);
        }
        #pragma unroll
        for (int off = 32; off; off >>= 1) s += __shfl_xor(s, off);
        if (lane == 0) Beta[wid * 16 + h] = 1.f / (1.f + __expf(-s));
    }
}

// In-place DPFP on fp16 spans of 128 (first 64 hold raw p, written by gemm MODE 1).
__global__ __launch_bounds__(256) void dpfp_h(half_t* __restrict__ P) {
    int gw   = (blockIdx.x * 256 + threadIdx.x) >> 6;
    int lane = threadIdx.x & 63;
    half_t* base = P + (size_t)gw * 128;
    float p  = (float)base[lane];
    float pm = __shfl(p, (lane + 63) & 63);           // p[lane-1], lane0 gets p[63]
    float rp  = fmaxf(p, 0.f),  rn  = fmaxf(-p, 0.f);
    float rpm = fmaxf(pm, 0.f), rnm = fmaxf(-pm, 0.f);
    float aprev = (lane == 0) ? rnm : rpm;            // xc[(lane-1)%128]
    float bprev = (lane == 0) ? rpm : rnm;            // xc[lane+63]
    float phi_a = rp * aprev;                         // phi[lane]
    float phi_b = rn * bprev;                         // phi[lane+64]
    float s = phi_a + phi_b;
    #pragma unroll
    for (int off = 32; off; off >>= 1) s += __shfl_xor(s, off);
    float inv = 1.f / (s + 1e-6f);
    base[lane]      = (half_t)(phi_a * inv);
    base[64 + lane] = (half_t)(phi_b * inv);
}

// ---- scan helpers: pair-lookahead (WY / delta-rule identity) ----
// Per pair of steps (even step E, odd step O), with w = state before the pair:
//   e0 = w.kE, e1 = w.kO, f0 = w.qE, f1 = w.qO   (4 independent reduces)
//   c0 = bE (vE - e0)
//   d1 = e1 + c0 * (kE.kO)            <- Gram scalar
//   c1 = bO (vO - d1)
//   y0 = f0 + c0 * (kE.qE)
//   y1 = f1 + c0 * (kE.qO) + c1 * (kO.qO)
//   w += c0 kE + c1 kO
// Gram scalars are row-independent -> precomputed once per chunk in LDS.
// (r7 lesson: depth-4 lookahead blows the register budget and the scheduler
// serializes the reduce chains — depth 2 is the local optimum.)
//
// LANE->COLUMN MAP (r9 bank-conflict fix): lane tc owns cols
// {tc*4..tc*4+3} u {64+tc*4..64+tc*4+3} so the two 16B ds_reads sit at
// 16B lane stride (banks 2-way aliased = free) instead of the old tc*8
// assignment's 32B stride (4-way conflict on EVERY hot-loop read —
// SQ_LDS_BANK_CONFLICT showed 152 cyc/pair).  Any static column
// permutation is exact as long as K, Q, w, and Gram all use it (they all
// go through LOADSTEP; w is private per-lane state).

#define LOADSTEP(DK, DQ, STEP)                                              \
    {                                                                       \
        floatx4 _ka = *(const floatx4*)&Ks[bufi][STEP][tc * 4];             \
        floatx4 _kb = *(const floatx4*)&Ks[bufi][STEP][64 + tc * 4];        \
        floatx4 _qa = *(const floatx4*)&Qs[bufi][STEP][tc * 4];             \
        floatx4 _qb = *(const floatx4*)&Qs[bufi][STEP][64 + tc * 4];        \
        for (int _i = 0; _i < 4; ++_i) {                                    \
            DK[_i] = _ka[_i]; DK[4 + _i] = _kb[_i];                         \
            DQ[_i] = _qa[_i]; DQ[4 + _i] = _qb[_i];                         \
        }                                                                   \
    }

#define DOT8(RES, X, Y)                                                     \
    {                                                                       \
        float _s0 = X[0] * Y[0], _s1 = X[1] * Y[1];                         \
        _s0 = fmaf(X[2], Y[2], _s0); _s1 = fmaf(X[3], Y[3], _s1);           \
        _s0 = fmaf(X[4], Y[4], _s0); _s1 = fmaf(X[5], Y[5], _s1);           \
        _s0 = fmaf(X[6], Y[6], _s0); _s1 = fmaf(X[7], Y[7], _s1);           \
        RES = _s0 + _s1;                                                    \
    }

// One pair: prefetch pair P+1 into the N* register set, 4 dots+reduces on C*,
// tiny serial part, batched w update, y stores.
#define PAIR(CEK, CEQ, COK, COQ, CEV, CEB, COV, COB, CG,                    \
             NEK, NEQ, NOK, NOQ, NEV, NEB, NOV, NOB, NG, P)                 \
    {                                                                       \
        if ((P) + 1 < 16) {                                                 \
            LOADSTEP(NEK, NEQ, 2 * (P) + 2);                                \
            LOADSTEP(NOK, NOQ, 2 * (P) + 3);                                \
            NEV = Vs[bufi][2 * (P) + 2][row_l];                             \
            NEB = Bs[bufi][2 * (P) + 2];                                    \
            NOV = Vs[bufi][2 * (P) + 3][row_l];                             \
            NOB = Bs[bufi][2 * (P) + 3];                                    \
            NG  = *(const floatx4*)&GramLDS[(P) + 1][0];                    \
        }                                                                   \
        float _e0, _e1, _f0, _f1;                                           \
        DOT8(_e0, w, CEK); DOT8(_e1, w, COK);                               \
        DOT8(_f0, w, CEQ); DOT8(_f1, w, COQ);                               \
        _e0 = row16_allreduce(_e0); _e1 = row16_allreduce(_e1);             \
        _f0 = row16_allreduce(_f0); _f1 = row16_allreduce(_f1);             \
        float _c0 = CEB * (CEV - _e0);                                      \
        float _d1 = fmaf(_c0, CG[0], _e1);                                  \
        float _c1 = COB * (COV - _d1);                                      \
        float _y0 = fmaf(_c0, CG[1], _f0);                                  \
        float _y1 = fmaf(_c1, CG[3], fmaf(_c0, CG[2], _f1));                \
        for (int _j = 0; _j < 8; ++_j)                                      \
            w[_j] = fmaf(_c1, COK[_j], fmaf(_c0, CEK[_j], w[_j]));          \
        if (tc == 0) {                                                      \
            ybase[(size_t)((cc * CHUNK + 2 * (P))     * BATCH + b) * 1024] = (half_t)_y0; \
            ybase[(size_t)((cc * CHUNK + 2 * (P) + 1) * BATCH + b) * 1024] = (half_t)_y1; \
        }                                                                   \
    }

// Sequential fast-weight scan, r0 geometry (proven): 256 blocks = 64 bh x 4
// row-chunks of 16 rows; 16 lanes/row, 8 fp32 state/lane; chunk staging with
// double-buffered LDS + register-held global prefetch.  Pair-lookahead inner
// loop (measured 660 us): the ~470-cyc dep chain is paid once per 2 steps and
// the pair's 4 reduces pipeline.
__global__ __launch_bounds__(256, 1) void scan_kernel(const half_t* __restrict__ PhiK,
                                                      const half_t* __restrict__ PhiQ,
                                                      const float* __restrict__ V,
                                                      const float* __restrict__ Beta,
                                                      half_t* __restrict__ Y) {
    __shared__ float Ks[2][CHUNK][128];   // 32 KB
    __shared__ float Qs[2][CHUNK][128];   // 32 KB
    __shared__ float Vs[2][CHUNK][16];    //  4 KB
    __shared__ float Bs[2][CHUNK];        // 256 B
    __shared__ float GramLDS[16][4];      // 256 B: per pair {kE.kO, kE.qE, kE.qO, kO.qO}

    const int bh = blockIdx.x >> 2;     // 0..63
    const int rc = blockIdx.x & 3;      // row chunk
    const int b = bh >> 4, h = bh & 15;
    const int tid = threadIdx.x;
    const int row_l = tid >> 4;         // 0..15
    const int tc = tid & 15;            // column group (8 floats)
    const int vrow = rc * 16 + row_l;   // 0..63

    const half_t* kg = PhiK + h * 128;
    const half_t* qg = PhiQ + h * 128;
    const float*  vg = V + h * 64 + rc * 16;
    const float*  bg = Beta + h;
    half_t* ybase = Y + h * 64 + vrow;

    // ---- stage chunk 0 directly ----
    {
        #pragma unroll
        for (int rpt = 0; rpt < 2; ++rpt) {
            int i = rpt * 256 + tid;              // 0..511
            int st = i >> 4, seg = i & 15, row = i & 15;
            size_t r = (size_t)(st * BATCH + b);
            half8 kv = *(const half8*)(kg + r * 2048 + seg * 8);
            half8 qv = *(const half8*)(qg + r * 2048 + seg * 8);
            floatx4 klo, khi, qlo, qhi;
            #pragma unroll
            for (int j = 0; j < 4; ++j) {
                klo[j] = (float)kv[j]; khi[j] = (float)kv[4 + j];
                qlo[j] = (float)qv[j]; qhi[j] = (float)qv[4 + j];
            }
            *(floatx4*)&Ks[0][st][seg * 8]     = klo;
            *(floatx4*)&Ks[0][st][seg * 8 + 4] = khi;
            *(floatx4*)&Qs[0][st][seg * 8]     = qlo;
            *(floatx4*)&Qs[0][st][seg * 8 + 4] = qhi;
            Vs[0][st][row] = vg[r * 1024 + row];
        }
        if (tid < CHUNK) {
            size_t r = (size_t)(tid * BATCH + b);
            Bs[0][tid] = bg[r * 16];
        }
    }
    __syncthreads();

    float w[8];
    #pragma unroll
    for (int j = 0; j < 8; ++j) w[j] = 0.f;

    for (int cc = 0; cc < NCHUNK; ++cc) {
        const int bufi = cc & 1;
        const bool more = (cc + 1 < NCHUNK);

        // ---- Gram precompute for chunk cc: row-group g handles pair g ----
        {
            float ka[8], kb[8], qa[8], qb[8];
            LOADSTEP(ka, qa, 2 * row_l);
            LOADSTEP(kb, qb, 2 * row_l + 1);
            float skk, s00, s01, s11;
            DOT8(skk, ka, kb);
            DOT8(s00, ka, qa);
            DOT8(s01, ka, qb);
            DOT8(s11, kb, qb);
            skk = row16_allreduce(skk);
            s00 = row16_allreduce(s00);
            s01 = row16_allreduce(s01);
            s11 = row16_allreduce(s11);
            if (tc == 0) {
                GramLDS[row_l][0] = skk;
                GramLDS[row_l][1] = s00;
                GramLDS[row_l][2] = s01;
                GramLDS[row_l][3] = s11;
            }
        }
        __syncthreads();   // Gram visible (LDS-only traffic -> cheap drain)

        // ---- issue global loads for chunk cc+1 (held in regs until after compute) ----
        half8 pk[2], pq[2];
        float pv[2], pb = 0.f;
        if (more) {
            #pragma unroll
            for (int rpt = 0; rpt < 2; ++rpt) {
                int i = rpt * 256 + tid;
                int st = i >> 4, seg = i & 15, row = i & 15;
                size_t r = (size_t)(((cc + 1) * CHUNK + st) * BATCH + b);
                pk[rpt] = *(const half8*)(kg + r * 2048 + seg * 8);
                pq[rpt] = *(const half8*)(qg + r * 2048 + seg * 8);
                pv[rpt] = vg[r * 1024 + row];
            }
            if (tid < CHUNK) {
                size_t r = (size_t)(((cc + 1) * CHUNK + tid) * BATCH + b);
                pb = bg[r * 16];
            }
        }

        // ---- preload pair 0 (set 0) ----
        float EK0[8], EQ0[8], OK0[8], OQ0[8];
        float EK1[8], EQ1[8], OK1[8], OQ1[8];
        float Ev0, Eb0, Ov0, Ob0, Ev1, Eb1, Ov1, Ob1;
        floatx4 G0, G1;
        LOADSTEP(EK0, EQ0, 0);
        LOADSTEP(OK0, OQ0, 1);
        Ev0 = Vs[bufi][0][row_l]; Eb0 = Bs[bufi][0];
        Ov0 = Vs[bufi][1][row_l]; Ob0 = Bs[bufi][1];
        G0 = *(const floatx4*)&GramLDS[0][0];

        // ---- 16 pairs, ping-pong register sets ----
        #pragma unroll 1
        for (int p2 = 0; p2 < 16; p2 += 2) {
            PAIR(EK0, EQ0, OK0, OQ0, Ev0, Eb0, Ov0, Ob0, G0,
                 EK1, EQ1, OK1, OQ1, Ev1, Eb1, Ov1, Ob1, G1, p2);
            PAIR(EK1, EQ1, OK1, OQ1, Ev1, Eb1, Ov1, Ob1, G1,
                 EK0, EQ0, OK0, OQ0, Ev0, Eb0, Ov0, Ob0, G0, p2 + 1);
        }

        // ---- write staged chunk cc+1 into the other buffer ----
        if (more) {
            const int bufn = bufi ^ 1;
            #pragma unroll
            for (int rpt = 0; rpt < 2; ++rpt) {
                int i = rpt * 256 + tid;
                int st = i >> 4, seg = i & 15, row = i & 15;
                floatx4 klo, khi, qlo, qhi;
                #pragma unroll
                for (int j = 0; j < 4; ++j) {
                    klo[j] = (float)pk[rpt][j]; khi[j] = (float)pk[rpt][4 + j];
                    qlo[j] = (float)pq[rpt][j]; qhi[j] = (float)pq[rpt][4 + j];
                }
                *(floatx4*)&Ks[bufn][st][seg * 8]     = klo;
                *(floatx4*)&Ks[bufn][st][seg * 8 + 4] = khi;
                *(floatx4*)&Qs[bufn][st][seg * 8]     = qlo;
                *(floatx4*)&Qs[bufn][st][seg * 8 + 4] = qhi;
                Vs[bufn][st][row] = pv[rpt];
            }
            if (tid < CHUNK) Bs[bufn][tid] = pb;
        }
        __syncthreads();
    }
}

extern "C" void kernel_launch(void* const* d_in, const int* in_sizes, int n_in,
                              void* d_out, int out_size, void* d_ws, size_t ws_size,
                              hipStream_t stream) {
    const float* x  = (const float*)d_in[0];
    const float* Wq = (const float*)d_in[1];
    const float* Wk = (const float*)d_in[2];
    const float* Wv = (const float*)d_in[3];
    const float* Wb = (const float*)d_in[4];
    const float* Wo = (const float*)d_in[5];
    const float* bo = (const float*)d_in[6];

    char* ws = (char*)d_ws;
    size_t off = 0;
    auto alloc = [&](size_t bytes) -> void* {
        void* p = ws + off;
        off += (bytes + 255) & ~(size_t)255;
        return p;
    };
    half_t* PhiQ = (half_t*)alloc((size_t)NROWS * 2048 * 2);  // 64 MB
    half_t* PhiK = (half_t*)alloc((size_t)NROWS * 2048 * 2);  // 64 MB
    half_t* Yb   = (half_t*)alloc((size_t)NROWS * 1024 * 2);  // 32 MB
    float*  Beta = (float*)alloc((size_t)NROWS * 16 * 4);     //  1 MB
    short*  Xh   = (short*)alloc((size_t)NROWS * 1024 * 2);   // 32 MB (reused for Yh)
    short*  Xl   = (short*)alloc((size_t)NROWS * 1024 * 2);   // 32 MB (reused for Yl)
    short*  Wqh  = (short*)alloc((size_t)1024 * 1024 * 2);    //  2 MB each
    short*  Wql  = (short*)alloc((size_t)1024 * 1024 * 2);
    short*  Wkh  = (short*)alloc((size_t)1024 * 1024 * 2);
    short*  Wkl  = (short*)alloc((size_t)1024 * 1024 * 2);
    short*  Wvh  = (short*)alloc((size_t)1024 * 1024 * 2);
    short*  Wvl  = (short*)alloc((size_t)1024 * 1024 * 2);
    short*  Woh  = (short*)alloc((size_t)1024 * 1024 * 2);
    short*  Wol  = (short*)alloc((size_t)1024 * 1024 * 2);
    float*  Wbt  = (float*)alloc((size_t)16 * 1024 * 4);
    float*  Vb   = (float*)d_out;  // V staged in d_out (fp32, dead before final GEMM)

    transpose_split<<<4096, 256, 0, stream>>>(Wq, Wqh, Wql, 1024, 1024);
    transpose_split<<<4096, 256, 0, stream>>>(Wk, Wkh, Wkl, 1024, 1024);
    transpose_split<<<4096, 256, 0, stream>>>(Wv, Wvh, Wvl, 1024, 1024);
    transpose_split<<<4096, 256, 0, stream>>>(Wo, Woh, Wol, 1024, 1024);
    transpose_k<<<64, 256, 0, stream>>>(Wb, Wbt, 1024, 16);
    split_f32<<<8192, 256, 0, stream>>>(x, Xh, Xl);   // 16384*1024 / 2048

    dim3 ggrid(NROWS / 128, DIM / 128);
    const int dgrid = (NROWS * 16) / 4;
    gemm_sb<1><<<ggrid, 256, 0, stream>>>(Xh, Xl, Wqh, Wql, PhiQ, nullptr, DIM, DIM);
    dpfp_h<<<dgrid, 256, 0, stream>>>(PhiQ);
    gemm_sb<1><<<ggrid, 256, 0, stream>>>(Xh, Xl, Wkh, Wkl, PhiK, nullptr, DIM, DIM);
    dpfp_h<<<dgrid, 256, 0, stream>>>(PhiK);
    gemm_sb<0><<<ggrid, 256, 0, stream>>>(Xh, Xl, Wvh, Wvl, Vb, nullptr, DIM, DIM);
    beta_kernel<<<NROWS / 4, 256, 0, stream>>>(x, Wbt, Beta);
    scan_kernel<<<256, 256, 0, stream>>>(PhiK, PhiQ, Vb, Beta, Yb);
    // x consumers are done; reuse Xh/Xl for the split of Yb
    split_f16<<<8192, 256, 0, stream>>>(Yb, Xh, Xl);
    gemm_sb<0><<<ggrid, 256, 0, stream>>>(Xh, Xl, Woh, Wol, d_out, bo, DIM, DIM);
}